// Round 13
// baseline (208.882 us; speedup 1.0000x reference)
//
#include <hip/hip_runtime.h>
#include <hip/hip_bf16.h>

// Problem constants
#define B_   256
#define L_   197
#define C_   768
#define H_   48
#define NA_  10
#define ROWS (B_ * L_)            // 50432
#define TR   48                   // K3 tile rows
#define XP   772                  // xs pitch (floats): 768 + 4 pad
#define NBLK ((ROWS + TR - 1) / TR)   // 1051 (last block: 32 rows)
#define OFF_SIM 38731776          // B*L*C
#define OFF_IDX 38731777

typedef __attribute__((ext_vector_type(8))) short short8;
typedef __attribute__((ext_vector_type(4))) short short4_t;
typedef __attribute__((ext_vector_type(4))) float f32x4;

static __device__ inline short f2bf(float f) {
    union { float f; unsigned u; } v; v.f = f;
    unsigned r = v.u + 0x7fffu + ((v.u >> 16) & 1u);   // round-to-nearest-even
    return (short)(r >> 16);
}

#define GL2LDS(g, l) __builtin_amdgcn_global_load_lds( \
    (const __attribute__((address_space(1))) void*)(g), \
    (__attribute__((address_space(3))) void*)(l), 16, 0, 0)

// ---------------------------------------------------------------------------
// Kw: convert ALL 10 adapters' W1 [10,48,768] and W2 [10,768,48] to bf16.
// W2 stored K-padded to 64 (zeros) so GEMM2 can use 16x16x32 mfma.
// ---------------------------------------------------------------------------
__global__ void kw_convert(const float* __restrict__ W1, const float* __restrict__ W2,
                           short* __restrict__ W1b, short* __restrict__ W2b) {
    int i = blockIdx.x * 256 + threadIdx.x;
    if (i < NA_ * H_ * C_)                     // 368640
        W1b[i] = f2bf(W1[i]);
    if (i < NA_ * C_ * 64) {                   // 491520
        int k  = i & 63;
        int nc = i >> 6;                       // a*768 + c
        W2b[i] = (k < H_) ? f2bf(W2[nc * H_ + k]) : (short)0;
    }
}

// ---------------------------------------------------------------------------
// K1a: partial sums over L. grid = B*4 blocks of 192 threads; thread t owns
// float4-column t. partial layout [b][seg][c] f32.
// ---------------------------------------------------------------------------
__global__ void k1a_partial(const float* __restrict__ x, float* __restrict__ partial) {
    int b = blockIdx.x >> 2, seg = blockIdx.x & 3;
    int l0 = seg * 50, l1 = l0 + 50; if (l1 > L_) l1 = L_;
    int t = threadIdx.x;                       // 0..191
    const float* xb = x + (size_t)b * L_ * C_ + t * 4;
    float4 s = {0.f, 0.f, 0.f, 0.f};
    #pragma unroll 5
    for (int l = l0; l < l1; ++l) {
        float4 v = *(const float4*)(xb + (size_t)l * C_);
        s.x += v.x; s.y += v.y; s.z += v.z; s.w += v.w;
    }
    *(float4*)(partial + ((size_t)b * 4 + seg) * C_ + t * 4) = s;
}

// ---------------------------------------------------------------------------
// K1b: per-b mean -> sims[b][k] (unchanged)
// ---------------------------------------------------------------------------
__global__ void k1b_sims(const float* __restrict__ partial, const float* __restrict__ akey,
                         float* __restrict__ sims) {
    __shared__ float red[21][256];
    int b = blockIdx.x, t = threadIdx.x;
    const float* p = partial + (size_t)b * 4 * C_;
    float m[3];
    #pragma unroll
    for (int j = 0; j < 3; ++j) {
        int c = t + j * 256;
        m[j] = (p[c] + p[C_ + c] + p[2 * C_ + c] + p[3 * C_ + c]) * (1.f / (float)L_);
    }
    red[0][t] = m[0] * m[0] + m[1] * m[1] + m[2] * m[2];
    #pragma unroll
    for (int k = 0; k < NA_; ++k) {
        float kd = 0.f, kq = 0.f;
        #pragma unroll
        for (int j = 0; j < 3; ++j) {
            float kv = akey[k * C_ + t + j * 256];
            kd += m[j] * kv; kq += kv * kv;
        }
        red[1 + k][t] = kd; red[11 + k][t] = kq;
    }
    __syncthreads();
    for (int s = 128; s > 0; s >>= 1) {
        if (t < s) {
            #pragma unroll
            for (int q = 0; q < 21; ++q) red[q][t] += red[q][t + s];
        }
        __syncthreads();
    }
    if (t < NA_) {
        float msq = red[0][0];
        sims[b * NA_ + t] = red[1 + t][0] * rsqrtf(fmaxf(red[11 + t][0], 1e-12f))
                                          * rsqrtf(fmaxf(msq, 1e-12f));
    }
}

// ---------------------------------------------------------------------------
// K2: single block. argmax + majority vote + reduce_sim + idx (unchanged)
// ---------------------------------------------------------------------------
__global__ void k2_select(const float* __restrict__ sims, float* __restrict__ out,
                          int* __restrict__ majorp) {
    __shared__ int counts[NA_];
    __shared__ int majorS;
    __shared__ float rs[256];
    int t = threadIdx.x;                       // = b
    float s[NA_];
    #pragma unroll
    for (int k = 0; k < NA_; ++k) s[k] = sims[t * NA_ + k];
    int best = 0; float bv = s[0];
    #pragma unroll
    for (int k = 1; k < NA_; ++k) { if (s[k] > bv) { bv = s[k]; best = k; } }
    if (t < NA_) counts[t] = 0;
    __syncthreads();
    atomicAdd(&counts[best], 1);
    __syncthreads();
    if (t == 0) {
        int mj = 0, mc = counts[0];
        #pragma unroll
        for (int k = 1; k < NA_; ++k) { if (counts[k] > mc) { mc = counts[k]; mj = k; } }
        majorS = mj; *majorp = mj;
    }
    __syncthreads();
    int mj = majorS;
    rs[t] = s[mj];
    __syncthreads();
    for (int st = 128; st > 0; st >>= 1) { if (t < st) rs[t] += rs[t + st]; __syncthreads(); }
    if (t == 0) out[OFF_SIM] = rs[0] * (1.f / (float)B_);
    out[OFF_IDX + t] = (float)mj;
}

// ---------------------------------------------------------------------------
// K3: fused adapter apply, canonical LDS-staged structure.
// grid = NBLK blocks x 192 threads (3 waves, wave w owns rows w*16..w*16+15).
// 1) stage: 48x global_load_lds (16B/lane) -> xs[48][772] f32, contiguous 1KB
//    per wave-instruction, fully async.
// 2) GEMM1: A-frags ds_read_b128 from xs (+cvt), W1 frags from global (L2-hot),
//    h -> hs[48][72] bf16 (K-padded to 64).
// 3) GEMM2: swapped-operand mfma (W2 as A); bias read + result write IN-PLACE
//    in xs (exact f32 bias; x never re-read from HBM).
// 4) sweep: contiguous stores, thread t owns cols 4t..4t+3 of each row.
// ---------------------------------------------------------------------------
__global__ void k3_apply(const float* __restrict__ x, const short* __restrict__ W1b,
                         const short* __restrict__ W2b, const int* __restrict__ majorp,
                         float* __restrict__ out) {
    __shared__ float xs[TR * XP];              // 148,224 B
    __shared__ short hs[TR * 72];              //   6,912 B
    const int major = *majorp;

    int t = threadIdx.x;                       // 0..191
    int w = t >> 6, l = t & 63;
    int rbase = blockIdx.x * TR;
    int nrows = ROWS - rbase; if (nrows > TR) nrows = TR;
    int lo16 = l & 15;
    int g = l >> 4;                            // 0..3
    int klane = g * 8;

    // ---- 1) stage x tile: contiguous async global->LDS ----
    {
        const float* xsrc = x + (size_t)rbase * C_ + t * 4;
        #pragma unroll
        for (int it = 0; it < TR; ++it) {
            if (it < nrows)
                GL2LDS(xsrc + (size_t)it * C_, &xs[it * XP + t * 4]);
        }
    }
    __syncthreads();

    const int wave_active = (w * 16) < nrows;  // wave-uniform
    int row_l = w * 16 + lo16;

    if (wave_active) {
        // zero the K-pad region [48,64) of this wave's 16 hs rows
        short4_t z = {0, 0, 0, 0};
        *(short4_t*)&hs[row_l * 72 + 48 + g * 4] = z;

        // ---- 2) GEMM1: h = relu(x_tile @ W1^T) ----
        const short* w1r = W1b + major * (H_ * C_) + lo16 * C_ + klane;
        f32x4 acc0 = {0,0,0,0}, acc1 = {0,0,0,0}, acc2 = {0,0,0,0};
        #pragma unroll
        for (int kk = 0; kk < 24; ++kk) {
            const int k0 = kk * 32;
            f32x4 xa = *(const f32x4*)&xs[row_l * XP + k0 + klane];
            f32x4 xb = *(const f32x4*)&xs[row_l * XP + k0 + klane + 4];
            short8 wa = *(const short8*)(w1r + k0);
            short8 wb = *(const short8*)(w1r + 16 * C_ + k0);
            short8 wc = *(const short8*)(w1r + 32 * C_ + k0);
            short8 af;
            af[0] = f2bf(xa[0]); af[1] = f2bf(xa[1]); af[2] = f2bf(xa[2]); af[3] = f2bf(xa[3]);
            af[4] = f2bf(xb[0]); af[5] = f2bf(xb[1]); af[6] = f2bf(xb[2]); af[7] = f2bf(xb[3]);
            acc0 = __builtin_amdgcn_mfma_f32_16x16x32_bf16(af, wa, acc0, 0, 0, 0);
            acc1 = __builtin_amdgcn_mfma_f32_16x16x32_bf16(af, wb, acc1, 0, 0, 0);
            acc2 = __builtin_amdgcn_mfma_f32_16x16x32_bf16(af, wc, acc2, 0, 0, 0);
        }
        // h tile -> LDS (D layout: col = lane&15, row = g*4 + q)
        {
            int hrow0 = w * 16 + g * 4;
            #pragma unroll
            for (int q = 0; q < 4; ++q) {
                hs[(hrow0 + q) * 72 +  0 + lo16] = f2bf(fmaxf(acc0[q], 0.f));
                hs[(hrow0 + q) * 72 + 16 + lo16] = f2bf(fmaxf(acc1[q], 0.f));
                hs[(hrow0 + q) * 72 + 32 + lo16] = f2bf(fmaxf(acc2[q], 0.f));
            }
        }

        // ---- 3) GEMM2 + bias, in-place in xs (h slab is wave-local) ----
        short8 hA = *(const short8*)&hs[row_l * 72 + klane];
        short8 hB = *(const short8*)&hs[row_l * 72 + 32 + klane];
        const short* w2r = W2b + (size_t)major * (C_ * 64) + lo16 * 64 + klane;
        #pragma unroll
        for (int it = 0; it < 48; ++it) {
            short8 p0 = *(const short8*)(w2r + it * 1024);
            short8 p1 = *(const short8*)(w2r + it * 1024 + 32);
            f32x4 acc = {0,0,0,0};
            acc = __builtin_amdgcn_mfma_f32_16x16x32_bf16(p0, hA, acc, 0, 0, 0);
            acc = __builtin_amdgcn_mfma_f32_16x16x32_bf16(p1, hB, acc, 0, 0, 0);
            float* xp = &xs[row_l * XP + it * 16 + g * 4];
            f32x4 xv = *(const f32x4*)xp;
            f32x4 ov;
            ov[0] = xv[0] + fmaxf(acc[0], 0.f);
            ov[1] = xv[1] + fmaxf(acc[1], 0.f);
            ov[2] = xv[2] + fmaxf(acc[2], 0.f);
            ov[3] = xv[3] + fmaxf(acc[3], 0.f);
            *(f32x4*)xp = ov;
        }
    }
    __syncthreads();

    // ---- 4) sweep: contiguous stores ----
    {
        float* od = out + (size_t)rbase * C_ + t * 4;
        #pragma unroll
        for (int it = 0; it < TR; ++it) {
            if (it < nrows) {
                f32x4 v = *(const f32x4*)&xs[it * XP + t * 4];
                *(f32x4*)(od + (size_t)it * C_) = v;
            }
        }
    }
}

// ---------------------------------------------------------------------------
extern "C" void kernel_launch(void* const* d_in, const int* in_sizes, int n_in,
                              void* d_out, int out_size, void* d_ws, size_t ws_size,
                              hipStream_t stream) {
    const float* x    = (const float*)d_in[0];
    const float* W1   = (const float*)d_in[1];
    const float* W2   = (const float*)d_in[2];
    const float* akey = (const float*)d_in[3];
    float* out = (float*)d_out;

    char* ws = (char*)d_ws;
    short* W1b     = (short*)ws;                       //   737,280 B
    short* W2b     = (short*)(ws + 737280);            //   983,040 B
    float* partial = (float*)(ws + 1720320);           // 3,145,728 B
    float* sims    = (float*)(ws + 4866048);           //    10,240 B
    int*   majorp  = (int*)(ws + 4876288);

    hipLaunchKernelGGL(kw_convert, dim3(1920), dim3(256), 0, stream, W1, W2, W1b, W2b);
    hipLaunchKernelGGL(k1a_partial, dim3(B_ * 4), dim3(192), 0, stream, x, partial);
    hipLaunchKernelGGL(k1b_sims, dim3(B_), dim3(256), 0, stream, partial, akey, sims);
    hipLaunchKernelGGL(k2_select, dim3(1), dim3(256), 0, stream, sims, out, majorp);
    hipLaunchKernelGGL(k3_apply, dim3(NBLK), dim3(192), 0, stream, x, W1b, W2b, majorp, out);
}

// Round 14
// 139.138 us; speedup vs baseline: 1.5013x; 1.5013x over previous
//
#include <hip/hip_runtime.h>
#include <hip/hip_bf16.h>

// Problem constants
#define B_   256
#define L_   197
#define C_   768
#define H_   48
#define NA_  10
#define ROWS (B_ * L_)            // 50432
#define TR   32                   // K3 tile rows; ROWS = 32*1576 exactly
#define XP   776                  // xs pitch in bf16 (768 + 8): row stride 1552B = 388 dw = 4 banks -> 2-way only
#define NBLK (ROWS / TR)          // 1576
#define OFF_SIM 38731776          // B*L*C
#define OFF_IDX 38731777

typedef __attribute__((ext_vector_type(8))) short short8;
typedef __attribute__((ext_vector_type(4))) short short4_t;
typedef __attribute__((ext_vector_type(4))) float f32x4;

static __device__ inline short f2bf(float f) {
    union { float f; unsigned u; } v; v.f = f;
    unsigned r = v.u + 0x7fffu + ((v.u >> 16) & 1u);   // round-to-nearest-even
    return (short)(r >> 16);
}
static __device__ inline float bf2f(short s) {
    union { unsigned u; float f; } v;
    v.u = ((unsigned)(unsigned short)s) << 16;
    return v.f;
}

// ---------------------------------------------------------------------------
// Kw: convert ALL 10 adapters' W1 [10,48,768] and W2 [10,768,48] to bf16.
// W2 stored K-padded to 64 (zeros) so GEMM2 can use 16x16x32 mfma.
// ---------------------------------------------------------------------------
__global__ void kw_convert(const float* __restrict__ W1, const float* __restrict__ W2,
                           short* __restrict__ W1b, short* __restrict__ W2b) {
    int i = blockIdx.x * 256 + threadIdx.x;
    if (i < NA_ * H_ * C_)                     // 368640
        W1b[i] = f2bf(W1[i]);
    if (i < NA_ * C_ * 64) {                   // 491520
        int k  = i & 63;
        int nc = i >> 6;                       // a*768 + c
        W2b[i] = (k < H_) ? f2bf(W2[nc * H_ + k]) : (short)0;
    }
}

// ---------------------------------------------------------------------------
// K1a: partial sums over L. grid = B*4 blocks of 192 threads; thread t owns
// float4-column t. partial layout [b][seg][c] f32.
// ---------------------------------------------------------------------------
__global__ void k1a_partial(const float* __restrict__ x, float* __restrict__ partial) {
    int b = blockIdx.x >> 2, seg = blockIdx.x & 3;
    int l0 = seg * 50, l1 = l0 + 50; if (l1 > L_) l1 = L_;
    int t = threadIdx.x;                       // 0..191
    const float* xb = x + (size_t)b * L_ * C_ + t * 4;
    float4 s = {0.f, 0.f, 0.f, 0.f};
    #pragma unroll 5
    for (int l = l0; l < l1; ++l) {
        float4 v = *(const float4*)(xb + (size_t)l * C_);
        s.x += v.x; s.y += v.y; s.z += v.z; s.w += v.w;
    }
    *(float4*)(partial + ((size_t)b * 4 + seg) * C_ + t * 4) = s;
}

// ---------------------------------------------------------------------------
// K1b: per-b mean -> sims[b][k] (unchanged)
// ---------------------------------------------------------------------------
__global__ void k1b_sims(const float* __restrict__ partial, const float* __restrict__ akey,
                         float* __restrict__ sims) {
    __shared__ float red[21][256];
    int b = blockIdx.x, t = threadIdx.x;
    const float* p = partial + (size_t)b * 4 * C_;
    float m[3];
    #pragma unroll
    for (int j = 0; j < 3; ++j) {
        int c = t + j * 256;
        m[j] = (p[c] + p[C_ + c] + p[2 * C_ + c] + p[3 * C_ + c]) * (1.f / (float)L_);
    }
    red[0][t] = m[0] * m[0] + m[1] * m[1] + m[2] * m[2];
    #pragma unroll
    for (int k = 0; k < NA_; ++k) {
        float kd = 0.f, kq = 0.f;
        #pragma unroll
        for (int j = 0; j < 3; ++j) {
            float kv = akey[k * C_ + t + j * 256];
            kd += m[j] * kv; kq += kv * kv;
        }
        red[1 + k][t] = kd; red[11 + k][t] = kq;
    }
    __syncthreads();
    for (int s = 128; s > 0; s >>= 1) {
        if (t < s) {
            #pragma unroll
            for (int q = 0; q < 21; ++q) red[q][t] += red[q][t + s];
        }
        __syncthreads();
    }
    if (t < NA_) {
        float msq = red[0][0];
        sims[b * NA_ + t] = red[1 + t][0] * rsqrtf(fmaxf(red[11 + t][0], 1e-12f))
                                          * rsqrtf(fmaxf(msq, 1e-12f));
    }
}

// ---------------------------------------------------------------------------
// K2: single block. argmax + majority vote + reduce_sim + idx (unchanged)
// ---------------------------------------------------------------------------
__global__ void k2_select(const float* __restrict__ sims, float* __restrict__ out,
                          int* __restrict__ majorp) {
    __shared__ int counts[NA_];
    __shared__ int majorS;
    __shared__ float rs[256];
    int t = threadIdx.x;                       // = b
    float s[NA_];
    #pragma unroll
    for (int k = 0; k < NA_; ++k) s[k] = sims[t * NA_ + k];
    int best = 0; float bv = s[0];
    #pragma unroll
    for (int k = 1; k < NA_; ++k) { if (s[k] > bv) { bv = s[k]; best = k; } }
    if (t < NA_) counts[t] = 0;
    __syncthreads();
    atomicAdd(&counts[best], 1);
    __syncthreads();
    if (t == 0) {
        int mj = 0, mc = counts[0];
        #pragma unroll
        for (int k = 1; k < NA_; ++k) { if (counts[k] > mc) { mc = counts[k]; mj = k; } }
        majorS = mj; *majorp = mj;
    }
    __syncthreads();
    int mj = majorS;
    rs[t] = s[mj];
    __syncthreads();
    for (int st = 128; st > 0; st >>= 1) { if (t < st) rs[t] += rs[t + st]; __syncthreads(); }
    if (t == 0) out[OFF_SIM] = rs[0] * (1.f / (float)B_);
    out[OFF_IDX + t] = (float)mj;
}

// ---------------------------------------------------------------------------
// K3: fused adapter apply, LDS-staged + occupancy-sized.
// grid = 1576 blocks x 256 threads (4 waves). LDS = 53.1 KB -> 3 blocks/CU
// (12 waves/CU = the grid's wave cap).
// stage: x tile -> xs bf16 [32][776]; each wave instr reads 1 KB of ONE row
//   (contiguous; 4 waves walk 4 adjacent rows -> page-friendly).
// GEMM1: A-frags ds_read_b128 from xs (2-way bank alias only); W1 from L2.
//   Wave (rhalf, nsel): rows rhalf*16.., n-tiles {0,1} or {2}. h -> hs bf16.
// GEMM2: swapped-operand mfma (W2 as A); 24 col-iters per wave; bias from
//   xs bf16 (err <= 0.016, budget 0.12); f32x4 stores.
// ---------------------------------------------------------------------------
__global__ void k3_apply(const float* __restrict__ x, const short* __restrict__ W1b,
                         const short* __restrict__ W2b, const int* __restrict__ majorp,
                         float* __restrict__ out) {
    __shared__ short xs[TR * XP];              // 49,664 B
    __shared__ short hs[TR * 72];              //  4,608 B
    const int major = *majorp;

    int t = threadIdx.x;                       // 0..255
    int w = t >> 6, l = t & 63;
    int rbase = blockIdx.x * TR;
    int lo16 = l & 15;
    int g = l >> 4;                            // 0..3
    int klane = g * 8;

    // ---- 1) stage x tile (f32 global -> bf16 LDS), fully contiguous ----
    {
        const float* xsrc = x + (size_t)rbase * C_;
        #pragma unroll
        for (int rg = 0; rg < 8; ++rg) {
            int row = rg * 4 + w;
            #pragma unroll
            for (int c = 0; c < 3; ++c) {
                int col = c * 256 + l * 4;
                f32x4 v = *(const f32x4*)(xsrc + (size_t)row * C_ + col);
                short4_t b;
                b[0] = f2bf(v[0]); b[1] = f2bf(v[1]);
                b[2] = f2bf(v[2]); b[3] = f2bf(v[3]);
                *(short4_t*)&xs[row * XP + col] = b;
            }
        }
    }
    __syncthreads();

    int rhalf = w >> 1;                        // 0/1: row half
    int nsel  = w & 1;                         // 0: n-tiles {0,1}; 1: {2}
    int row_l = rhalf * 16 + lo16;

    // ---- 2) GEMM1: h = relu(x_tile @ W1^T) ----
    {
        const short* w1r = W1b + major * (H_ * C_) + lo16 * C_ + klane;
        if (nsel == 0) {
            // zero the K-pad region [48,64) of this half's 16 hs rows
            short4_t z = {0, 0, 0, 0};
            *(short4_t*)&hs[row_l * 72 + 48 + g * 4] = z;
            f32x4 acc0 = {0,0,0,0}, acc1 = {0,0,0,0};
            #pragma unroll
            for (int kk = 0; kk < 24; ++kk) {
                const int k0 = kk * 32;
                short8 xa = *(const short8*)&xs[row_l * XP + k0 + klane];
                short8 wa = *(const short8*)(w1r + k0);
                short8 wb = *(const short8*)(w1r + 16 * C_ + k0);
                acc0 = __builtin_amdgcn_mfma_f32_16x16x32_bf16(xa, wa, acc0, 0, 0, 0);
                acc1 = __builtin_amdgcn_mfma_f32_16x16x32_bf16(xa, wb, acc1, 0, 0, 0);
            }
            int hrow0 = rhalf * 16 + g * 4;
            #pragma unroll
            for (int q = 0; q < 4; ++q) {
                hs[(hrow0 + q) * 72 +  0 + lo16] = f2bf(fmaxf(acc0[q], 0.f));
                hs[(hrow0 + q) * 72 + 16 + lo16] = f2bf(fmaxf(acc1[q], 0.f));
            }
        } else {
            f32x4 acc2 = {0,0,0,0};
            #pragma unroll
            for (int kk = 0; kk < 24; ++kk) {
                const int k0 = kk * 32;
                short8 xa = *(const short8*)&xs[row_l * XP + k0 + klane];
                short8 wc = *(const short8*)(w1r + 32 * C_ + k0);
                acc2 = __builtin_amdgcn_mfma_f32_16x16x32_bf16(xa, wc, acc2, 0, 0, 0);
            }
            int hrow0 = rhalf * 16 + g * 4;
            #pragma unroll
            for (int q = 0; q < 4; ++q)
                hs[(hrow0 + q) * 72 + 32 + lo16] = f2bf(fmaxf(acc2[q], 0.f));
        }
    }
    __syncthreads();

    // ---- 3) GEMM2 + bias + store: 24 col-iters per wave ----
    {
        short8 hA = *(const short8*)&hs[row_l * 72 + klane];
        short8 hB = *(const short8*)&hs[row_l * 72 + 32 + klane];
        const int itbase = nsel * 24;
        const short* w2r = W2b + (size_t)major * (C_ * 64)
                               + (size_t)(itbase * 16 + lo16) * 64 + klane;
        const short* xbp = &xs[row_l * XP + itbase * 16 + g * 4];
        float* outr = out + (size_t)(rbase + row_l) * C_ + itbase * 16 + g * 4;
        #pragma unroll
        for (int it = 0; it < 24; ++it) {
            short8 p0 = *(const short8*)(w2r + it * 1024);
            short8 p1 = *(const short8*)(w2r + it * 1024 + 32);
            f32x4 acc = {0,0,0,0};
            acc = __builtin_amdgcn_mfma_f32_16x16x32_bf16(p0, hA, acc, 0, 0, 0);
            acc = __builtin_amdgcn_mfma_f32_16x16x32_bf16(p1, hB, acc, 0, 0, 0);
            short4_t xbv = *(const short4_t*)(xbp + it * 16);
            f32x4 ov;
            ov[0] = bf2f(xbv[0]) + fmaxf(acc[0], 0.f);
            ov[1] = bf2f(xbv[1]) + fmaxf(acc[1], 0.f);
            ov[2] = bf2f(xbv[2]) + fmaxf(acc[2], 0.f);
            ov[3] = bf2f(xbv[3]) + fmaxf(acc[3], 0.f);
            *(f32x4*)(outr + it * 16) = ov;
        }
    }
}

// ---------------------------------------------------------------------------
extern "C" void kernel_launch(void* const* d_in, const int* in_sizes, int n_in,
                              void* d_out, int out_size, void* d_ws, size_t ws_size,
                              hipStream_t stream) {
    const float* x    = (const float*)d_in[0];
    const float* W1   = (const float*)d_in[1];
    const float* W2   = (const float*)d_in[2];
    const float* akey = (const float*)d_in[3];
    float* out = (float*)d_out;

    char* ws = (char*)d_ws;
    short* W1b     = (short*)ws;                       //   737,280 B
    short* W2b     = (short*)(ws + 737280);            //   983,040 B
    float* partial = (float*)(ws + 1720320);           // 3,145,728 B
    float* sims    = (float*)(ws + 4866048);           //    10,240 B
    int*   majorp  = (int*)(ws + 4876288);

    hipLaunchKernelGGL(kw_convert, dim3(1920), dim3(256), 0, stream, W1, W2, W1b, W2b);
    hipLaunchKernelGGL(k1a_partial, dim3(B_ * 4), dim3(192), 0, stream, x, partial);
    hipLaunchKernelGGL(k1b_sims, dim3(B_), dim3(256), 0, stream, partial, akey, sims);
    hipLaunchKernelGGL(k2_select, dim3(1), dim3(256), 0, stream, sims, out, majorp);
    hipLaunchKernelGGL(k3_apply, dim3(NBLK), dim3(256), 0, stream, x, W1b, W2b, majorp, out);
}

// Round 17
// 128.581 us; speedup vs baseline: 1.6245x; 1.0821x over previous
//
#include <hip/hip_runtime.h>
#include <hip/hip_bf16.h>

// Problem constants
#define B_   256
#define L_   197
#define C_   768
#define H_   48
#define NA_  10
#define ROWS (B_ * L_)            // 50432
#define TR   16                   // K3 tile rows; 50432 = 16*3152 exactly
#define XP   772                  // xs pitch (f32): 768+4
#define HP   72                   // hs pitch (bf16): 64+8 (16B-aligned rows)
#define NBLK (ROWS / TR)          // 3152
#define OFF_SIM 38731776          // B*L*C
#define OFF_IDX 38731777

typedef __attribute__((ext_vector_type(8))) short short8;
typedef __attribute__((ext_vector_type(4))) short short4_t;
typedef __attribute__((ext_vector_type(4))) float f32x4;

static __device__ inline short f2bf(float f) {
    union { float f; unsigned u; } v; v.f = f;
    unsigned r = v.u + 0x7fffu + ((v.u >> 16) & 1u);   // round-to-nearest-even
    return (short)(r >> 16);
}

#define GL2LDS(g, l) __builtin_amdgcn_global_load_lds( \
    (const __attribute__((address_space(1))) void*)(g), \
    (__attribute__((address_space(3))) void*)(l), 16, 0, 0)

#define GLW(dst, p, OFF) asm volatile("global_load_dwordx4 %0, %1, off offset:" OFF \
    : "=v"(dst) : "v"(p))

// ---------------------------------------------------------------------------
// Kw: convert ALL 10 adapters' W1 [10,48,768] and W2 [10,768,48] to bf16.
// W2 stored K-padded to 64 (zeros) so GEMM2 can use 16x16x32 mfma.
// ---------------------------------------------------------------------------
__global__ void kw_convert(const float* __restrict__ W1, const float* __restrict__ W2,
                           short* __restrict__ W1b, short* __restrict__ W2b) {
    int i = blockIdx.x * 256 + threadIdx.x;
    if (i < NA_ * H_ * C_)                     // 368640
        W1b[i] = f2bf(W1[i]);
    if (i < NA_ * C_ * 64) {                   // 491520
        int k  = i & 63;
        int nc = i >> 6;                       // a*768 + c
        W2b[i] = (k < H_) ? f2bf(W2[nc * H_ + k]) : (short)0;
    }
}

// ---------------------------------------------------------------------------
// K1a: partial sums over L. grid = B*4 blocks of 192 threads.
// ---------------------------------------------------------------------------
__global__ void k1a_partial(const float* __restrict__ x, float* __restrict__ partial) {
    int b = blockIdx.x >> 2, seg = blockIdx.x & 3;
    int l0 = seg * 50, l1 = l0 + 50; if (l1 > L_) l1 = L_;
    int t = threadIdx.x;                       // 0..191
    const float* xb = x + (size_t)b * L_ * C_ + t * 4;
    float4 s = {0.f, 0.f, 0.f, 0.f};
    #pragma unroll 5
    for (int l = l0; l < l1; ++l) {
        float4 v = *(const float4*)(xb + (size_t)l * C_);
        s.x += v.x; s.y += v.y; s.z += v.z; s.w += v.w;
    }
    *(float4*)(partial + ((size_t)b * 4 + seg) * C_ + t * 4) = s;
}

// ---------------------------------------------------------------------------
// K1b: per-b mean -> sims[b][k] (unchanged)
// ---------------------------------------------------------------------------
__global__ void k1b_sims(const float* __restrict__ partial, const float* __restrict__ akey,
                         float* __restrict__ sims) {
    __shared__ float red[21][256];
    int b = blockIdx.x, t = threadIdx.x;
    const float* p = partial + (size_t)b * 4 * C_;
    float m[3];
    #pragma unroll
    for (int j = 0; j < 3; ++j) {
        int c = t + j * 256;
        m[j] = (p[c] + p[C_ + c] + p[2 * C_ + c] + p[3 * C_ + c]) * (1.f / (float)L_);
    }
    red[0][t] = m[0] * m[0] + m[1] * m[1] + m[2] * m[2];
    #pragma unroll
    for (int k = 0; k < NA_; ++k) {
        float kd = 0.f, kq = 0.f;
        #pragma unroll
        for (int j = 0; j < 3; ++j) {
            float kv = akey[k * C_ + t + j * 256];
            kd += m[j] * kv; kq += kv * kv;
        }
        red[1 + k][t] = kd; red[11 + k][t] = kq;
    }
    __syncthreads();
    for (int s = 128; s > 0; s >>= 1) {
        if (t < s) {
            #pragma unroll
            for (int q = 0; q < 21; ++q) red[q][t] += red[q][t + s];
        }
        __syncthreads();
    }
    if (t < NA_) {
        float msq = red[0][0];
        sims[b * NA_ + t] = red[1 + t][0] * rsqrtf(fmaxf(red[11 + t][0], 1e-12f))
                                          * rsqrtf(fmaxf(msq, 1e-12f));
    }
}

// ---------------------------------------------------------------------------
// K2: single block. argmax + majority vote + reduce_sim + idx (unchanged)
// ---------------------------------------------------------------------------
__global__ void k2_select(const float* __restrict__ sims, float* __restrict__ out,
                          int* __restrict__ majorp) {
    __shared__ int counts[NA_];
    __shared__ int majorS;
    __shared__ float rs[256];
    int t = threadIdx.x;                       // = b
    float s[NA_];
    #pragma unroll
    for (int k = 0; k < NA_; ++k) s[k] = sims[t * NA_ + k];
    int best = 0; float bv = s[0];
    #pragma unroll
    for (int k = 1; k < NA_; ++k) { if (s[k] > bv) { bv = s[k]; best = k; } }
    if (t < NA_) counts[t] = 0;
    __syncthreads();
    atomicAdd(&counts[best], 1);
    __syncthreads();
    if (t == 0) {
        int mj = 0, mc = counts[0];
        #pragma unroll
        for (int k = 1; k < NA_; ++k) { if (counts[k] > mc) { mc = counts[k]; mj = k; } }
        majorS = mj; *majorp = mj;
    }
    __syncthreads();
    int mj = majorS;
    rs[t] = s[mj];
    __syncthreads();
    for (int st = 128; st > 0; st >>= 1) { if (t < st) rs[t] += rs[t + st]; __syncthreads(); }
    if (t == 0) out[OFF_SIM] = rs[0] * (1.f / (float)B_);
    out[OFF_IDX + t] = (float)mj;
}

// ---------------------------------------------------------------------------
// K3: fused adapter apply. grid = 3152 blocks x 192 threads (3 waves).
// LDS 51.7KB -> 3 blocks/CU. Stage: x tile f32 via async global_load_lds
// (contiguous 1KB/instr; wave w stages col-segment w of every row). GEMM1:
// wave w = n-tile w; W1 frags in 2 forced-asm bursts of 12 (L2-hot); x frags
// ds_read from xs + cvt. h -> hs bf16 (K-pad 64). GEMM2: 16 col-iters/wave,
// W2 frags in 4 forced bursts of 8; bias f32 from xs; result in-place to xs.
// Sweep: contiguous stores (thread t owns floats 4t..4t+3 of each row).
// launch_bounds(192,2): 256-VGPR budget so burst regs never spill.
// ---------------------------------------------------------------------------
__launch_bounds__(192, 2)
__global__ void k3_apply(const float* __restrict__ x, const short* __restrict__ W1b,
                         const short* __restrict__ W2b, const int* __restrict__ majorp,
                         float* __restrict__ out) {
    __shared__ float xs[TR * XP];              // 49,408 B
    __shared__ short hs[TR * HP];              //  2,304 B
    const int major = *majorp;

    int t = threadIdx.x;                       // 0..191
    int w = t >> 6, l = t & 63;
    int rbase = blockIdx.x * TR;
    int lo16 = l & 15;
    int g = l >> 4;                            // 0..3
    int klane = g * 8;

    // ---- 1) stage x tile f32: async, contiguous (wave w -> col seg w) ----
    {
        const float* xsrc = x + (size_t)rbase * C_ + w * 256 + l * 4;
        #pragma unroll
        for (int i = 0; i < TR; ++i)
            GL2LDS(xsrc + (size_t)i * C_, &xs[i * XP + w * 256]);
    }
    __syncthreads();

    // ---- 2) GEMM1: wave w computes n-tile w of h = relu(x @ W1^T) ----
    {
        const short* w1p = W1b + major * (H_ * C_) + (size_t)(w * 16 + lo16) * C_ + klane;
        f32x4 acc = {0, 0, 0, 0};
        short8 q0, q1, q2, q3, q4, q5, q6, q7, q8, q9, q10, q11;

#define G1STEP(KK, Q) { \
        const int k0 = (KK) * 32; \
        f32x4 xa = *(const f32x4*)&xs[lo16 * XP + k0 + klane]; \
        f32x4 xb = *(const f32x4*)&xs[lo16 * XP + k0 + klane + 4]; \
        short8 af; \
        af[0] = f2bf(xa[0]); af[1] = f2bf(xa[1]); af[2] = f2bf(xa[2]); af[3] = f2bf(xa[3]); \
        af[4] = f2bf(xb[0]); af[5] = f2bf(xb[1]); af[6] = f2bf(xb[2]); af[7] = f2bf(xb[3]); \
        acc = __builtin_amdgcn_mfma_f32_16x16x32_bf16(af, Q, acc, 0, 0, 0); }

        // burst A: k-iters 0..11 (byte offsets kk*64)
        GLW(q0, w1p, "0");    GLW(q1, w1p, "64");   GLW(q2, w1p, "128");
        GLW(q3, w1p, "192");  GLW(q4, w1p, "256");  GLW(q5, w1p, "320");
        GLW(q6, w1p, "384");  GLW(q7, w1p, "448");  GLW(q8, w1p, "512");
        GLW(q9, w1p, "576");  GLW(q10, w1p, "640"); GLW(q11, w1p, "704");
        asm volatile("s_waitcnt vmcnt(0)"
            : "+v"(q0), "+v"(q1), "+v"(q2), "+v"(q3), "+v"(q4), "+v"(q5),
              "+v"(q6), "+v"(q7), "+v"(q8), "+v"(q9), "+v"(q10), "+v"(q11));
        __builtin_amdgcn_sched_barrier(0);
        G1STEP(0, q0)  G1STEP(1, q1)  G1STEP(2, q2)  G1STEP(3, q3)
        G1STEP(4, q4)  G1STEP(5, q5)  G1STEP(6, q6)  G1STEP(7, q7)
        G1STEP(8, q8)  G1STEP(9, q9)  G1STEP(10, q10) G1STEP(11, q11)

        // burst B: k-iters 12..23 (offsets 768..1472)
        GLW(q0, w1p, "768");  GLW(q1, w1p, "832");  GLW(q2, w1p, "896");
        GLW(q3, w1p, "960");  GLW(q4, w1p, "1024"); GLW(q5, w1p, "1088");
        GLW(q6, w1p, "1152"); GLW(q7, w1p, "1216"); GLW(q8, w1p, "1280");
        GLW(q9, w1p, "1344"); GLW(q10, w1p, "1408"); GLW(q11, w1p, "1472");
        asm volatile("s_waitcnt vmcnt(0)"
            : "+v"(q0), "+v"(q1), "+v"(q2), "+v"(q3), "+v"(q4), "+v"(q5),
              "+v"(q6), "+v"(q7), "+v"(q8), "+v"(q9), "+v"(q10), "+v"(q11));
        __builtin_amdgcn_sched_barrier(0);
        G1STEP(12, q0) G1STEP(13, q1) G1STEP(14, q2) G1STEP(15, q3)
        G1STEP(16, q4) G1STEP(17, q5) G1STEP(18, q6) G1STEP(19, q7)
        G1STEP(20, q8) G1STEP(21, q9) G1STEP(22, q10) G1STEP(23, q11)
#undef G1STEP

        // h -> hs (D: col n=lo16 (W1 row), row m=g*4+q (x row))
        #pragma unroll
        for (int q = 0; q < 4; ++q)
            hs[(g * 4 + q) * HP + w * 16 + lo16] = f2bf(fmaxf(acc[q], 0.f));
        // K-pad zero [48,64): wave 0 covers 16 rows x 16 cols
        if (w == 0) {
            short4_t z = {0, 0, 0, 0};
            *(short4_t*)&hs[lo16 * HP + 48 + g * 4] = z;
        }
    }
    __syncthreads();

    // ---- 3) GEMM2 + bias, in-place in xs. Wave w: col-iters w*16..w*16+15 ----
    {
        short8 hA = *(const short8*)&hs[lo16 * HP + klane];
        short8 hB = *(const short8*)&hs[lo16 * HP + 32 + klane];
        const short* w2base = W2b + (size_t)major * (C_ * 64) + lo16 * 64 + klane;

        #pragma unroll
        for (int b = 0; b < 4; ++b) {
            const int j0 = b * 4;
            const short* pa = w2base + (size_t)(w * 16 + j0) * 1024;
            const short* pb = pa + 2048;
            short8 r00, r01, r10, r11, r20, r21, r30, r31;
            GLW(r00, pa, "0");    GLW(r01, pa, "64");
            GLW(r10, pa, "2048"); GLW(r11, pa, "2112");
            GLW(r20, pb, "0");    GLW(r21, pb, "64");
            GLW(r30, pb, "2048"); GLW(r31, pb, "2112");
            asm volatile("s_waitcnt vmcnt(0)"
                : "+v"(r00), "+v"(r01), "+v"(r10), "+v"(r11),
                  "+v"(r20), "+v"(r21), "+v"(r30), "+v"(r31));
            __builtin_amdgcn_sched_barrier(0);

#define G2STEP(JJ, P0, P1) { \
            const int it = w * 16 + j0 + (JJ); \
            f32x4 acc = {0, 0, 0, 0}; \
            acc = __builtin_amdgcn_mfma_f32_16x16x32_bf16(P0, hA, acc, 0, 0, 0); \
            acc = __builtin_amdgcn_mfma_f32_16x16x32_bf16(P1, hB, acc, 0, 0, 0); \
            float* xp = &xs[lo16 * XP + it * 16 + g * 4]; \
            f32x4 xv = *(const f32x4*)xp; \
            f32x4 ov; \
            ov[0] = xv[0] + fmaxf(acc[0], 0.f); \
            ov[1] = xv[1] + fmaxf(acc[1], 0.f); \
            ov[2] = xv[2] + fmaxf(acc[2], 0.f); \
            ov[3] = xv[3] + fmaxf(acc[3], 0.f); \
            *(f32x4*)xp = ov; }

            G2STEP(0, r00, r01) G2STEP(1, r10, r11)
            G2STEP(2, r20, r21) G2STEP(3, r30, r31)
#undef G2STEP
        }
    }
    __syncthreads();

    // ---- 4) sweep: contiguous stores (768 = 192 threads x 4 floats) ----
    {
        float* od = out + (size_t)rbase * C_ + t * 4;
        #pragma unroll
        for (int row = 0; row < TR; ++row) {
            f32x4 v = *(const f32x4*)&xs[row * XP + t * 4];
            *(f32x4*)(od + (size_t)row * C_) = v;
        }
    }
}

// ---------------------------------------------------------------------------
extern "C" void kernel_launch(void* const* d_in, const int* in_sizes, int n_in,
                              void* d_out, int out_size, void* d_ws, size_t ws_size,
                              hipStream_t stream) {
    const float* x    = (const float*)d_in[0];
    const float* W1   = (const float*)d_in[1];
    const float* W2   = (const float*)d_in[2];
    const float* akey = (const float*)d_in[3];
    float* out = (float*)d_out;

    char* ws = (char*)d_ws;
    short* W1b     = (short*)ws;                       //   737,280 B
    short* W2b     = (short*)(ws + 737280);            //   983,040 B
    float* partial = (float*)(ws + 1720320);           // 3,145,728 B
    float* sims    = (float*)(ws + 4866048);           //    10,240 B
    int*   majorp  = (int*)(ws + 4876288);

    hipLaunchKernelGGL(kw_convert, dim3(1920), dim3(256), 0, stream, W1, W2, W1b, W2b);
    hipLaunchKernelGGL(k1a_partial, dim3(B_ * 4), dim3(192), 0, stream, x, partial);
    hipLaunchKernelGGL(k1b_sims, dim3(B_), dim3(256), 0, stream, partial, akey, sims);
    hipLaunchKernelGGL(k2_select, dim3(1), dim3(256), 0, stream, sims, out, majorp);
    hipLaunchKernelGGL(k3_apply, dim3(NBLK), dim3(192), 0, stream, x, W1b, W2b, majorp, out);
}